// Round 1
// baseline (6629.904 us; speedup 1.0000x reference)
//
#include <hip/hip_runtime.h>
#include <cmath>

#define RN 512
#define RT 1024
#define RB 64

// 256 blocks x 512 threads. 4 blocks per batch; each block owns 128 output rows,
// W slice register-resident (32 x float4 = 128 VGPR per thread, 4 threads/row).
// Exchange of tanh(h) between the 4 blocks goes through the output buffer itself
// (unique address per timestep), synchronized by a per-batch monotonic counter.
__global__ void __launch_bounds__(512, 2) rnn_step_kernel(
    const float* __restrict__ h0,
    const float* __restrict__ X,
    const float* __restrict__ W,
    float* __restrict__ outH,
    unsigned int* __restrict__ ctr)
{
    const int bid  = blockIdx.x;
    // group the 4 blocks of a batch on one XCD (round-robin heuristic: xcd = bid % 8)
    const int xcd  = bid & 7;
    const int slot = bid >> 3;               // 0..31
    const int batch = xcd * 8 + (slot >> 2); // 0..63
    const int part  = slot & 3;              // 0..3
    const int rowbase = part * 128;

    const int tid = threadIdx.x;
    const int r = tid >> 2;      // 0..127 : row within slice
    const int c = tid & 3;       // 0..3   : k-chunk (128 wide)
    const int row = rowbase + r;

    __shared__ __align__(16) float tanh_lds[RN];
    __shared__ float x_lds[128];

    // W slice into registers: thread (r,c) holds W[row][c*128 .. c*128+127]
    float4 w4[32];
    {
        const float4* Wrow = reinterpret_cast<const float4*>(W + (size_t)row * RN + c * 128);
        #pragma unroll
        for (int jj = 0; jj < 32; ++jj) w4[jj] = Wrow[jj];
    }

    float h = h0[row];
    unsigned int* myctr = ctr + batch * 32;  // 128B stride to avoid line contention

    for (int t = 0; t < RT; ++t) {
        // stage tanh(h_t) (full N) and this slice's x into LDS
        if (t == 0) {
            tanh_lds[tid] = tanhf(h0[tid]);
        } else {
            tanh_lds[tid] = outH[((size_t)batch * RT + (t - 1)) * RN + tid];
        }
        if (tid < 128) {
            x_lds[tid] = X[((size_t)batch * RT + t) * RN + rowbase + tid];
        }
        __syncthreads();  // stage -> compute

        // partial dot over this thread's 128-wide k-chunk
        float dot = 0.f;
        const float4* th4 = reinterpret_cast<const float4*>(tanh_lds + c * 128);
        #pragma unroll
        for (int jj = 0; jj < 32; ++jj) {
            float4 tv = th4[jj];
            dot = fmaf(w4[jj].x, tv.x, dot);
            dot = fmaf(w4[jj].y, tv.y, dot);
            dot = fmaf(w4[jj].z, tv.z, dot);
            dot = fmaf(w4[jj].w, tv.w, dot);
        }
        // reduce across the 4 k-chunk threads (consecutive lanes)
        dot += __shfl_xor(dot, 1);
        dot += __shfl_xor(dot, 2);

        h = 0.9f * h + 0.1f * (dot + x_lds[r]);   // replicated identically x4
        float th = tanhf(h);

        if (c == 0) {
            outH[((size_t)batch * RT + t) * RN + row] = th;
        }
        __syncthreads();  // drains vmcnt(0): stores visible in L2; also closes LDS reads

        if (t != RT - 1) {
            if (tid == 0) {
                __hip_atomic_fetch_add(myctr, 1u, __ATOMIC_RELEASE, __HIP_MEMORY_SCOPE_AGENT);
                const unsigned int target = 4u * (unsigned)(t + 1);
                while (__hip_atomic_load(myctr, __ATOMIC_ACQUIRE, __HIP_MEMORY_SCOPE_AGENT) < target) {
                    __builtin_amdgcn_s_sleep(2);
                }
            }
            __syncthreads();  // broadcast barrier completion to the block
        }
    }
}

// geometry epilogue: geo[b,t,:] = hidden[b,t,:] @ Gw^T + Gb ; one wave per (b,t)
__global__ void geom_kernel(const float* __restrict__ hid,
                            const float* __restrict__ Gw,
                            const float* __restrict__ Gb,
                            float* __restrict__ geo)
{
    const int wid  = (blockIdx.x * blockDim.x + threadIdx.x) >> 6;
    const int lane = threadIdx.x & 63;
    if (wid >= RB * RT) return;
    const float* rowp = hid + (size_t)wid * RN;
    float g0 = 0.f, g1 = 0.f;
    #pragma unroll
    for (int j = 0; j < 8; ++j) {
        float v = rowp[lane + 64 * j];
        g0 = fmaf(v, Gw[lane + 64 * j], g0);
        g1 = fmaf(v, Gw[RN + lane + 64 * j], g1);
    }
    #pragma unroll
    for (int m = 32; m >= 1; m >>= 1) {
        g0 += __shfl_xor(g0, m);
        g1 += __shfl_xor(g1, m);
    }
    if (lane == 0) {
        geo[(size_t)wid * 2]     = g0 + Gb[0];
        geo[(size_t)wid * 2 + 1] = g1 + Gb[1];
    }
}

__global__ void init_ctr(unsigned int* ctr)
{
    int i = blockIdx.x * blockDim.x + threadIdx.x;
    if (i < 64 * 32) ctr[i] = 0u;
}

extern "C" void kernel_launch(void* const* d_in, const int* in_sizes, int n_in,
                              void* d_out, int out_size, void* d_ws, size_t ws_size,
                              hipStream_t stream)
{
    const float* h0 = (const float*)d_in[0];
    const float* X  = (const float*)d_in[1];
    const float* W  = (const float*)d_in[2];
    const float* Gw = (const float*)d_in[3];
    const float* Gb = (const float*)d_in[4];

    float* outH = (float*)d_out;
    float* geo  = outH + (size_t)RB * RT * RN;
    unsigned int* ctr = (unsigned int*)d_ws;

    // counters must be zeroed every launch (ws is poisoned once, never re-poisoned)
    init_ctr<<<8, 256, 0, stream>>>(ctr);

    void* kargs[] = { (void*)&h0, (void*)&X, (void*)&W, (void*)&outH, (void*)&ctr };
    hipLaunchCooperativeKernel(rnn_step_kernel, dim3(256), dim3(512), kargs, 0, stream);

    geom_kernel<<<(RB * RT * 64 + 255) / 256, 256, 0, stream>>>(outH, Gw, Gb, geo);
}

// Round 2
// 5594.416 us; speedup vs baseline: 1.1851x; 1.1851x over previous
//
#include <hip/hip_runtime.h>
#include <cmath>

#define RN 512
#define RT 1024
#define RB 64

// 256 blocks x 512 threads, 4 blocks per batch (grouped on one XCD by bid%8
// round-robin heuristic; correctness via agent-scope acquire/release either way).
// Each block owns 128 output rows. Thread (q=tid>>4, c16=tid&15) holds
// W[rowbase+4q .. +3][c16*32 .. +31] in 32 float4 registers (forced live via
// asm), computes 4 partial dots over its 32-wide k-chunk from LDS-staged
// tanh(h), reduces across the 16 c16-lanes with shfl_xor, and the 4 owner
// lanes (c16<4) do the h-update/tanh/store. Cross-block exchange of tanh(h)
// goes through the output buffer (unique address per step) with a per-batch
// monotonic atomic counter barrier.
__global__ void __launch_bounds__(512, 2) rnn_step_kernel(
    const float* __restrict__ h0,
    const float* __restrict__ X,
    const float* __restrict__ W,
    float* __restrict__ outH,
    unsigned int* __restrict__ ctr)
{
    const int bid  = blockIdx.x;
    const int xcd  = bid & 7;
    const int slot = bid >> 3;               // 0..31
    const int batch = xcd * 8 + (slot >> 2); // 0..63
    const int part  = slot & 3;              // 0..3
    const int rowbase = part * 128;

    const int tid = threadIdx.x;
    const int q   = tid >> 4;                // 0..31 : row-quad within slice
    const int c16 = tid & 15;                // 0..15 : 32-wide k-chunk

    __shared__ __align__(16) float tanh_lds[RN];

    // W slice into registers, stored in bank-rotated jj order:
    // w[i][jj] = W[rowbase+4q+i][c16*32 + ((jj+c16)&7)*4 .. +3]
    float4 w[4][8];
    #pragma unroll
    for (int i = 0; i < 4; ++i) {
        const float* Wr = W + (size_t)(rowbase + q * 4 + i) * RN + c16 * 32;
        #pragma unroll
        for (int jj = 0; jj < 8; ++jj) {
            const int jr = (jj + c16) & 7;
            float4 v = *reinterpret_cast<const float4*>(Wr + jr * 4);
            // opaque: forces materialization in VGPRs, forbids re-load inside loop
            asm volatile("" : "+v"(v.x), "+v"(v.y), "+v"(v.z), "+v"(v.w));
            w[i][jj] = v;
        }
    }

    const bool owner = (c16 < 4);
    const int myrow = rowbase + q * 4 + c16;   // valid when owner
    float h = 0.f, xv = 0.f;
    if (owner) {
        h  = h0[myrow];
        xv = X[(size_t)batch * RT * RN + myrow];   // x for t=0
    }

    tanh_lds[tid] = tanhf(h0[tid]);            // prologue stage of tanh(h_0)

    unsigned int* myctr = ctr + batch * 32;    // 128B stride per batch

    for (int t = 0; t < RT; ++t) {
        __syncthreads();   // tanh_lds ready (prologue or previous exchange)

        // partial dots over this thread's 32-wide k-chunk, 4 rows
        float d0 = 0.f, d1 = 0.f, d2 = 0.f, d3 = 0.f;
        const float4* tp = reinterpret_cast<const float4*>(tanh_lds + c16 * 32);
        #pragma unroll
        for (int jj = 0; jj < 8; ++jj) {
            const int jr = (jj + c16) & 7;     // bank rotation: start bank 4*jr
            float4 tv = tp[jr];
            d0 = fmaf(w[0][jj].x, tv.x, d0);
            d0 = fmaf(w[0][jj].y, tv.y, d0);
            d0 = fmaf(w[0][jj].z, tv.z, d0);
            d0 = fmaf(w[0][jj].w, tv.w, d0);
            d1 = fmaf(w[1][jj].x, tv.x, d1);
            d1 = fmaf(w[1][jj].y, tv.y, d1);
            d1 = fmaf(w[1][jj].z, tv.z, d1);
            d1 = fmaf(w[1][jj].w, tv.w, d1);
            d2 = fmaf(w[2][jj].x, tv.x, d2);
            d2 = fmaf(w[2][jj].y, tv.y, d2);
            d2 = fmaf(w[2][jj].z, tv.z, d2);
            d2 = fmaf(w[2][jj].w, tv.w, d2);
            d3 = fmaf(w[3][jj].x, tv.x, d3);
            d3 = fmaf(w[3][jj].y, tv.y, d3);
            d3 = fmaf(w[3][jj].z, tv.z, d3);
            d3 = fmaf(w[3][jj].w, tv.w, d3);
        }
        // reduce across the 16 c16-lanes (xor stays inside the 16-lane group)
        #pragma unroll
        for (int m = 1; m <= 8; m <<= 1) {
            d0 += __shfl_xor(d0, m);
            d1 += __shfl_xor(d1, m);
            d2 += __shfl_xor(d2, m);
            d3 += __shfl_xor(d3, m);
        }

        if (owner) {
            const float dot = (c16 == 0) ? d0 : (c16 == 1) ? d1 : (c16 == 2) ? d2 : d3;
            h = 0.9f * h + 0.1f * (dot + xv);
            const float th = tanhf(h);
            outH[((size_t)batch * RT + t) * RN + myrow] = th;
            if (t + 1 < RT)   // prefetch next x during the barrier
                xv = X[((size_t)batch * RT + (t + 1)) * RN + myrow];
        }

        __syncthreads();   // drains vmcnt(0): th stores visible; LDS reads done

        if (t + 1 < RT) {
            if (tid == 0) {
                __hip_atomic_fetch_add(myctr, 1u, __ATOMIC_RELEASE, __HIP_MEMORY_SCOPE_AGENT);
                const unsigned int target = 4u * (unsigned)(t + 1);
                while (__hip_atomic_load(myctr, __ATOMIC_ACQUIRE, __HIP_MEMORY_SCOPE_AGENT) < target) {
                    __builtin_amdgcn_s_sleep(1);
                }
            }
            __syncthreads();  // broadcast barrier completion
            // exchange: reload full tanh(h_t) (all 4 parts) from outH
            tanh_lds[tid] = outH[((size_t)batch * RT + t) * RN + tid];
        }
    }
}

// geometry epilogue: geo[b,t,:] = hidden[b,t,:] @ Gw^T + Gb ; one wave per (b,t)
__global__ void geom_kernel(const float* __restrict__ hid,
                            const float* __restrict__ Gw,
                            const float* __restrict__ Gb,
                            float* __restrict__ geo)
{
    const int wid  = (blockIdx.x * blockDim.x + threadIdx.x) >> 6;
    const int lane = threadIdx.x & 63;
    if (wid >= RB * RT) return;
    const float* rowp = hid + (size_t)wid * RN;
    float g0 = 0.f, g1 = 0.f;
    #pragma unroll
    for (int j = 0; j < 8; ++j) {
        float v = rowp[lane + 64 * j];
        g0 = fmaf(v, Gw[lane + 64 * j], g0);
        g1 = fmaf(v, Gw[RN + lane + 64 * j], g1);
    }
    #pragma unroll
    for (int m = 32; m >= 1; m >>= 1) {
        g0 += __shfl_xor(g0, m);
        g1 += __shfl_xor(g1, m);
    }
    if (lane == 0) {
        geo[(size_t)wid * 2]     = g0 + Gb[0];
        geo[(size_t)wid * 2 + 1] = g1 + Gb[1];
    }
}

__global__ void init_ctr(unsigned int* ctr)
{
    int i = blockIdx.x * blockDim.x + threadIdx.x;
    if (i < 64 * 32) ctr[i] = 0u;
}

extern "C" void kernel_launch(void* const* d_in, const int* in_sizes, int n_in,
                              void* d_out, int out_size, void* d_ws, size_t ws_size,
                              hipStream_t stream)
{
    const float* h0 = (const float*)d_in[0];
    const float* X  = (const float*)d_in[1];
    const float* W  = (const float*)d_in[2];
    const float* Gw = (const float*)d_in[3];
    const float* Gb = (const float*)d_in[4];

    float* outH = (float*)d_out;
    float* geo  = outH + (size_t)RB * RT * RN;
    unsigned int* ctr = (unsigned int*)d_ws;

    // counters must be zeroed every launch (ws poisoned once, never re-poisoned)
    init_ctr<<<8, 256, 0, stream>>>(ctr);

    void* kargs[] = { (void*)&h0, (void*)&X, (void*)&W, (void*)&outH, (void*)&ctr };
    hipLaunchCooperativeKernel(rnn_step_kernel, dim3(256), dim3(512), kargs, 0, stream);

    geom_kernel<<<(RB * RT * 64 + 255) / 256, 256, 0, stream>>>(outH, Gw, Gb, geo);
}